// Round 10
// baseline (152.268 us; speedup 1.0000x reference)
//
#include <hip/hip_runtime.h>
#include <hip/hip_bf16.h>

// x: [32,128,32,32] f32 -> N=32768 positions, D=128; emb: [512,128] f32.
// d_out: out0 quantized_st (4194304) | loss (1) | indices (32768) | usage (1)
//
// NUMERICS ARE CORRECTNESS-CRITICAL (verified passing rounds 2/4/5/6/7/8/9):
//  - esq/fsq: numpy pairwise 8-accumulator pattern, squares rounded pre-sum
//  - dot: single sequential FMA chain over c = 0..127 ascending
//  - dist: s = fl( fl(fsq + esq) - 2*dot ), tie -> lowest index
//  - loss: dq f32; square f32; accumulate f64
// Do not change per-element accumulation order.
//
// R10 change (perf only): __launch_bounds__(256,2) -> (256,1). R9's (256,2)
// capped VGPR at 128 (empirical hipcc model: ~65536-reg/CU pool divided by
// threads*arg2 -> R5:64, R7:64, R9:128 all match) while the 16x8 tile's live
// set is ~200 -> 22MB scratch spill (FETCH 33MB, WRITE 38.6MB), 138us.
// Cap 256 lets acc[16][8] stay in registers: 2 waves/SIMD, 2 blocks/CU
// (LDS 39KB). Pipe model: LDS/VALU ratio = 6(I+J)/IJ = 1.125 at 16x8.

#define DCH    128
#define KCODES 512
#define NELEM  4194304
#define POSB   64          // positions per block
#define NBLK   512         // 32768/64
#define NTHR   256

#define OFF_LOSS  4194304
#define OFF_IDX   4194305
#define OFF_USAGE 4227073

// ws layout: flags 512*4 @0 | esq 512*4 @2048 | partials 512*8 @4096

__device__ __forceinline__ float round_barrier(float v) {
    asm volatile("" : "+v"(v));
    return v;
}

// ---------------- prep: ||e_k||^2 (numpy order) + zero flags ----------------
__global__ __launch_bounds__(512) void vq_prep(const float* __restrict__ emb,
                                               float* __restrict__ esq,
                                               int* __restrict__ flags) {
    int k = threadIdx.x;
    const float* row = emb + (size_t)k * DCH;
    float r[8];
#pragma unroll
    for (int j = 0; j < 8; ++j) { float v = row[j]; r[j] = round_barrier(v * v); }
#pragma unroll
    for (int i = 8; i < DCH; i += 8) {
#pragma unroll
        for (int j = 0; j < 8; ++j) {
            float v = row[i + j];
            float sq = round_barrier(v * v);
            r[j] += sq;
        }
    }
    esq[k] = ((r[0] + r[1]) + (r[2] + r[3])) + ((r[4] + r[5]) + (r[6] + r[7]));
    flags[k] = 0;
}

// ---------------- main: distances + argmin + gather/STE + loss partials ----
// 512 blocks x 256 threads. Block: 64 positions vs all 512 codes.
// ty = wave (4 pos groups of 16), tx = lane. Lane owns codes {4tx..4tx+3} and
// {256+4tx..256+4tx+3}. acc[16][8]: i = position, j = code slot.
__global__ __launch_bounds__(256, 1) void vq_main(const float* __restrict__ x,
                                                  const float* __restrict__ emb,
                                                  const float* __restrict__ esq,
                                                  int* __restrict__ flags,
                                                  float* __restrict__ out0,
                                                  float* __restrict__ out_idx,
                                                  double* __restrict__ partials) {
    __shared__ __align__(16) float xt[16][64];      // 4 KB  (c-chunk x tile)
    __shared__ __align__(16) float et[16][512];     // 32 KB (c-chunk emb^T, swizzled)
    __shared__ float esq_s[KCODES];                 // 2 KB
    __shared__ float sfsq[POSB];
    __shared__ int   sbi[POSB];

    const int t   = threadIdx.x;
    const int n0  = blockIdx.x * POSB;
    const int b   = n0 >> 10;
    const int hw0 = n0 & 1023;
    const float* xb = x + (size_t)b * DCH * 1024 + hw0;

    // stage esq table
    esq_s[t]       = esq[t];
    esq_s[t + 256] = esq[t + 256];

    // fsq: one thread per position, full numpy 8-accumulator pattern from
    // global (coalesced across the 64 threads per (i,j) step).
    if (t < POSB) {
        float r[8];
#pragma unroll
        for (int j = 0; j < 8; ++j) {
            float v = xb[(size_t)j * 1024 + t];
            r[j] = round_barrier(v * v);
        }
#pragma unroll
        for (int i = 1; i < 16; ++i) {
#pragma unroll
            for (int j = 0; j < 8; ++j) {
                float v = xb[(size_t)(8 * i + j) * 1024 + t];
                float sq = round_barrier(v * v);
                r[j] += sq;
            }
        }
        sfsq[t] = ((r[0] + r[1]) + (r[2] + r[3])) + ((r[4] + r[5]) + (r[6] + r[7]));
    }

    const int ty = t >> 6;    // wave id: pos group (ty*16 .. ty*16+15)
    const int tx = t & 63;    // lane
    const int kst = t >> 2;   // staging: k lane base (0..63, +64r)
    const int jst = t & 3;    // float4 slot within 16-c chunk

    float acc[16][8];
#pragma unroll
    for (int i = 0; i < 16; ++i)
#pragma unroll
        for (int j = 0; j < 8; ++j) acc[i][j] = 0.f;

    for (int cc = 0; cc < 8; ++cc) {
        __syncthreads();  // prev compute done before overwriting et/xt

        // stage x chunk: xt[cl][p4..p4+3], cl = t>>4, p4 = (t&15)*4
        {
            const int cl = t >> 4;
            const int p4 = (t & 15) * 4;
            float4 v = *reinterpret_cast<const float4*>(
                xb + (size_t)(cc * 16 + cl) * 1024 + p4);
            *reinterpret_cast<float4*>(&xt[cl][p4]) = v;
        }
        // stage emb chunk transposed + XOR col swizzle: et[cl][k ^ ((cl&7)<<2)]
#pragma unroll
        for (int r = 0; r < 8; ++r) {
            const int k = kst + 64 * r;
            float4 v = *reinterpret_cast<const float4*>(
                emb + (size_t)k * DCH + cc * 16 + jst * 4);
            float va[4] = {v.x, v.y, v.z, v.w};
#pragma unroll
            for (int w = 0; w < 4; ++w) {
                const int cl = jst * 4 + w;
                et[cl][k ^ ((cl & 7) << 2)] = va[w];
            }
        }
        __syncthreads();

        // 16x8 register tile; xt reads wave-uniform broadcasts; et reads
        // conflict-free b128 (granule = lane ^ uniform).
#pragma unroll
        for (int cl = 0; cl < 16; ++cl) {
            const int s = (cl & 7) << 2;
            float4 xv0 = *reinterpret_cast<const float4*>(&xt[cl][ty * 16]);
            float4 xv1 = *reinterpret_cast<const float4*>(&xt[cl][ty * 16 + 4]);
            float4 xv2 = *reinterpret_cast<const float4*>(&xt[cl][ty * 16 + 8]);
            float4 xv3 = *reinterpret_cast<const float4*>(&xt[cl][ty * 16 + 12]);
            float4 ev0 = *reinterpret_cast<const float4*>(&et[cl][(tx * 4) ^ s]);
            float4 ev1 = *reinterpret_cast<const float4*>(&et[cl][256 + ((tx * 4) ^ s)]);
            float xa[16] = {xv0.x, xv0.y, xv0.z, xv0.w, xv1.x, xv1.y, xv1.z, xv1.w,
                            xv2.x, xv2.y, xv2.z, xv2.w, xv3.x, xv3.y, xv3.z, xv3.w};
            float ea[8]  = {ev0.x, ev0.y, ev0.z, ev0.w, ev1.x, ev1.y, ev1.z, ev1.w};
#pragma unroll
            for (int i = 0; i < 16; ++i)
#pragma unroll
                for (int j = 0; j < 8; ++j)
                    acc[i][j] = __builtin_fmaf(xa[i], ea[j], acc[i][j]);
        }
    }

    // fold distances + per-thread argmin (ascending global k within thread)
    float bd[16];
    int   bi[16];
#pragma unroll
    for (int i = 0; i < 16; ++i) { bd[i] = 3.4e38f; bi[i] = 0; }
#pragma unroll
    for (int j = 0; j < 8; ++j) {
        const int kg = (j < 4) ? (tx * 4 + j) : (256 + tx * 4 + (j - 4));
        const float eq = esq_s[kg];
#pragma unroll
        for (int i = 0; i < 16; ++i) {
            float A = sfsq[ty * 16 + i] + eq;  // rounds once (ulp ~1.5e-5)
            float s = A - 2.f * acc[i][j];     // 2*acc exact; rounds once
            if (s < bd[i]) { bd[i] = s; bi[i] = kg; }
        }
    }
    // 64-lane butterfly reduce, lexicographic (d, idx)
#pragma unroll
    for (int m = 1; m < 64; m <<= 1) {
#pragma unroll
        for (int i = 0; i < 16; ++i) {
            float d2 = __shfl_xor(bd[i], m, 64);
            int   i2 = __shfl_xor(bi[i], m, 64);
            if (d2 < bd[i] || (d2 == bd[i] && i2 < bi[i])) { bd[i] = d2; bi[i] = i2; }
        }
    }
    if (tx == 0) {
#pragma unroll
        for (int i = 0; i < 16; ++i) {
            const int p = ty * 16 + i;
            out_idx[n0 + p] = (float)bi[i];
            sbi[p] = bi[i];
            flags[bi[i]] = 1;   // benign same-value race
        }
    }
    __syncthreads();

    // fused gather + straight-through write + f64 loss partial
    double local = 0.0;
    {
        const int cl8 = t >> 4;          // 0..15 (c row base)
        const int p4  = (t & 15) * 4;    // 0..60
        const int i0 = sbi[p4], i1 = sbi[p4 + 1], i2 = sbi[p4 + 2], i3 = sbi[p4 + 3];
#pragma unroll
        for (int it = 0; it < 8; ++it) {
            const int c = it * 16 + cl8;
            float4 xv = *reinterpret_cast<const float4*>(xb + (size_t)c * 1024 + p4);
            float q0 = emb[(size_t)i0 * DCH + c];
            float q1 = emb[(size_t)i1 * DCH + c];
            float q2 = emb[(size_t)i2 * DCH + c];
            float q3 = emb[(size_t)i3 * DCH + c];
            float d0 = q0 - xv.x, d1 = q1 - xv.y, d2 = q2 - xv.z, d3 = q3 - xv.w;
            float4 o = {xv.x + d0, xv.y + d1, xv.z + d2, xv.w + d3};
            *reinterpret_cast<float4*>(
                out0 + (size_t)(b * DCH + c) * 1024 + hw0 + p4) = o;
            local += (double)(d0 * d0);
            local += (double)(d1 * d1);
            local += (double)(d2 * d2);
            local += (double)(d3 * d3);
        }
    }
    // block f64 reduce (reuse et; last reads were before the post-fold barrier)
    double* sd = reinterpret_cast<double*>(&et[0][0]);
    sd[t] = local;
    __syncthreads();
    for (int s = 128; s > 0; s >>= 1) {
        if (t < s) sd[t] += sd[t + s];
        __syncthreads();
    }
    if (t == 0) partials[blockIdx.x] = sd[0];
}

// ---------------- finalize: loss + usage ----------------
__global__ __launch_bounds__(512) void vq_final(const double* __restrict__ partials,
                                                const int* __restrict__ flags,
                                                float* __restrict__ out_loss,
                                                float* __restrict__ out_usage) {
    __shared__ double sd[512];
    __shared__ int    si[512];
    const int t = threadIdx.x;
    sd[t] = partials[t];      // 512 blocks -> one partial per thread
    si[t] = flags[t];
    __syncthreads();
    for (int k = 256; k > 0; k >>= 1) {
        if (t < k) { sd[t] += sd[t + k]; si[t] += si[t + k]; }
        __syncthreads();
    }
    if (t == 0) {
        float m = (float)(sd[0] / (double)NELEM);
        *out_loss  = m + 0.25f * m;
        *out_usage = (float)si[0] / (float)KCODES;
    }
}

extern "C" void kernel_launch(void* const* d_in, const int* in_sizes, int n_in,
                              void* d_out, int out_size, void* d_ws, size_t ws_size,
                              hipStream_t stream) {
    const float* x   = (const float*)d_in[0];
    const float* emb = (const float*)d_in[1];
    float* out = (float*)d_out;

    float* out0      = out;
    float* out_loss  = out + OFF_LOSS;
    float* out_idx   = out + OFF_IDX;
    float* out_usage = out + OFF_USAGE;

    char* ws = (char*)d_ws;
    int*    ws_flags = (int*)ws;
    float*  ws_esq   = (float*)(ws + 2048);
    double* ws_part  = (double*)(ws + 4096);

    vq_prep <<<1,    512, 0, stream>>>(emb, ws_esq, ws_flags);
    vq_main <<<NBLK, NTHR, 0, stream>>>(x, emb, ws_esq, ws_flags, out0, out_idx, ws_part);
    vq_final<<<1,    512, 0, stream>>>(ws_part, ws_flags, out_loss, out_usage);
}

// Round 11
// 133.978 us; speedup vs baseline: 1.1365x; 1.1365x over previous
//
#include <hip/hip_runtime.h>
#include <hip/hip_bf16.h>

// x: [32,128,32,32] f32 -> N=32768 positions, D=128; emb: [512,128] f32.
// d_out: out0 quantized_st (4194304) | loss (1) | indices (32768) | usage (1)
//
// NUMERICS ARE CORRECTNESS-CRITICAL (verified passing rounds 2/4/5/6/7/8/9/10):
//  - esq/fsq: numpy pairwise 8-accumulator pattern, squares rounded pre-sum
//  - dot: single sequential FMA chain over c = 0..127 ascending
//  - dist: s = fl( fl(fsq + esq) - 2*dot ), tie -> lowest index
//  - loss: dq f32; square f32; accumulate f64
// Do not change per-element accumulation order.
//
// R11 change (perf only): R2-R10 analysis -> ~86us plateau is LDS-PIPE bound
// (R6: 4 b128 LDS reads per 64 FMA -> LDS 12.3k cyc/CU/chunk vs VALU 8.2k).
// The xt reads are WAVE-UNIFORM -> move x off the LDS pipe entirely: read x
// directly from global with readfirstlane-forced uniform addresses (scalar /
// constant-cache path). xt array and its staging deleted; et-only LDS.
// Geometry = proven R6 (acc[8][8], 1024 blk x 256 thr, 4 waves/SIMD).

#define DCH    128
#define KCODES 512
#define NELEM  4194304
#define POSB   32          // positions per block
#define NBLK   1024        // 32768/32
#define NTHR   256

#define OFF_LOSS  4194304
#define OFF_IDX   4194305
#define OFF_USAGE 4227073

// ws layout: flags 512*4 @0 | esq 512*4 @2048 | partials 1024*8 @4096

__device__ __forceinline__ float round_barrier(float v) {
    asm volatile("" : "+v"(v));
    return v;
}

// ---------------- prep: ||e_k||^2 (numpy order) + zero flags ----------------
__global__ __launch_bounds__(512) void vq_prep(const float* __restrict__ emb,
                                               float* __restrict__ esq,
                                               int* __restrict__ flags) {
    int k = threadIdx.x;
    const float* row = emb + (size_t)k * DCH;
    float r[8];
#pragma unroll
    for (int j = 0; j < 8; ++j) { float v = row[j]; r[j] = round_barrier(v * v); }
#pragma unroll
    for (int i = 8; i < DCH; i += 8) {
#pragma unroll
        for (int j = 0; j < 8; ++j) {
            float v = row[i + j];
            float sq = round_barrier(v * v);
            r[j] += sq;
        }
    }
    esq[k] = ((r[0] + r[1]) + (r[2] + r[3])) + ((r[4] + r[5]) + (r[6] + r[7]));
    flags[k] = 0;
}

// ---------------- main: distances + argmin + gather/STE + loss partials ----
// 1024 blocks x 256 threads. Block: 32 positions vs all 512 codes.
// ty = wave (4 pos groups of 8), tx = lane. Lane owns codes {4tx..4tx+3} and
// {256+4tx..256+4tx+3}. acc[8][8]: i = position, j = code slot.
// x operand comes from global via wave-uniform (scalar-path) loads.
__global__ __launch_bounds__(256, 2) void vq_main(const float* __restrict__ x,
                                                  const float* __restrict__ emb,
                                                  const float* __restrict__ esq,
                                                  int* __restrict__ flags,
                                                  float* __restrict__ out0,
                                                  float* __restrict__ out_idx,
                                                  double* __restrict__ partials) {
    __shared__ __align__(16) float et[16][512];     // 32 KB (c-chunk emb^T, swizzled)
    __shared__ float esq_s[KCODES];                 // 2 KB
    __shared__ float sfsq[POSB];
    __shared__ int   sbi[POSB];

    const int t   = threadIdx.x;
    const int n0  = blockIdx.x * POSB;
    const int b   = n0 >> 10;
    const int hw0 = n0 & 1023;
    const float* xb = x + (size_t)b * DCH * 1024 + hw0;

    // stage esq table
    esq_s[t]       = esq[t];
    esq_s[t + 256] = esq[t + 256];

    // fsq, numpy 8-accumulator: thread (p = t>>3, j = t&7) does r_j for pos p.
    // Partials in et scratch; consumed before chunk-0 staging overwrites it.
    {
        const int p = t >> 3, j = t & 7;
        float r;
        {
            float v = xb[(size_t)j * 1024 + p];
            r = round_barrier(v * v);
        }
#pragma unroll
        for (int i = 1; i < 16; ++i) {
            float v = xb[(size_t)(8 * i + j) * 1024 + p];
            float sq = round_barrier(v * v);
            r += sq;
        }
        float (*sr)[POSB] = (float (*)[POSB]) & et[0][0];
        sr[j][p] = r;
    }
    __syncthreads();
    if (t < POSB) {
        float (*sr)[POSB] = (float (*)[POSB]) & et[0][0];
        sfsq[t] = ((sr[0][t] + sr[1][t]) + (sr[2][t] + sr[3][t]))
                + ((sr[4][t] + sr[5][t]) + (sr[6][t] + sr[7][t]));
    }

    const int ty = t >> 6;    // wave id = pos group
    const int tx = t & 63;    // lane
    // wave-uniform x base offset (readfirstlane forces scalar path)
    const int tyu = __builtin_amdgcn_readfirstlane(ty);

    float acc[8][8];
#pragma unroll
    for (int i = 0; i < 8; ++i)
#pragma unroll
        for (int j = 0; j < 8; ++j) acc[i][j] = 0.f;

    const int kst = t >> 2;   // staging: k lane base (coalesced emb reads)
    const int jst = t & 3;    // float4 slot within 16-c chunk

    for (int cc = 0; cc < 8; ++cc) {
        __syncthreads();  // prev compute done (and sr consumed at cc=0)

        // stage emb chunk transposed + XOR col swizzle: et[cl][k ^ ((cl&7)<<2)]
#pragma unroll
        for (int r = 0; r < 8; ++r) {
            const int k = kst + 64 * r;
            float4 v = *reinterpret_cast<const float4*>(
                emb + (size_t)k * DCH + cc * 16 + jst * 4);
            float va[4] = {v.x, v.y, v.z, v.w};
#pragma unroll
            for (int w = 0; w < 4; ++w) {
                const int cl = jst * 4 + w;
                et[cl][k ^ ((cl & 7) << 2)] = va[w];
            }
        }
        __syncthreads();

        // 8x8 register tile; x from global via wave-uniform loads (off the
        // LDS pipe); et reads conflict-free b128 (granule = lane ^ uniform).
#pragma unroll
        for (int cl = 0; cl < 16; ++cl) {
            const int s = (cl & 7) << 2;
            const int xoff = (cc * 16 + cl) * 1024 + tyu * 8;  // uniform
            float4 ev0 = *reinterpret_cast<const float4*>(&et[cl][(tx * 4) ^ s]);
            float4 ev1 = *reinterpret_cast<const float4*>(&et[cl][256 + ((tx * 4) ^ s)]);
            float xa[8];
#pragma unroll
            for (int i = 0; i < 8; ++i) xa[i] = xb[xoff + i];
            float ea[8] = {ev0.x, ev0.y, ev0.z, ev0.w, ev1.x, ev1.y, ev1.z, ev1.w};
#pragma unroll
            for (int i = 0; i < 8; ++i)
#pragma unroll
                for (int j = 0; j < 8; ++j)
                    acc[i][j] = __builtin_fmaf(xa[i], ea[j], acc[i][j]);
        }
    }

    // fold distances + per-thread argmin (ascending global k within thread)
    float bd[8];
    int   bi[8];
#pragma unroll
    for (int i = 0; i < 8; ++i) { bd[i] = 3.4e38f; bi[i] = 0; }
#pragma unroll
    for (int j = 0; j < 8; ++j) {
        const int kg = (j < 4) ? (tx * 4 + j) : (256 + tx * 4 + (j - 4));
        const float eq = esq_s[kg];
#pragma unroll
        for (int i = 0; i < 8; ++i) {
            float A = sfsq[ty * 8 + i] + eq;   // rounds once (ulp ~1.5e-5)
            float s = A - 2.f * acc[i][j];     // 2*acc exact; rounds once
            if (s < bd[i]) { bd[i] = s; bi[i] = kg; }
        }
    }
    // 64-lane butterfly reduce, lexicographic (d, idx)
#pragma unroll
    for (int m = 1; m < 64; m <<= 1) {
#pragma unroll
        for (int i = 0; i < 8; ++i) {
            float d2 = __shfl_xor(bd[i], m, 64);
            int   i2 = __shfl_xor(bi[i], m, 64);
            if (d2 < bd[i] || (d2 == bd[i] && i2 < bi[i])) { bd[i] = d2; bi[i] = i2; }
        }
    }
    if (tx == 0) {
#pragma unroll
        for (int i = 0; i < 8; ++i) {
            const int p = ty * 8 + i;
            out_idx[n0 + p] = (float)bi[i];
            sbi[p] = bi[i];
            flags[bi[i]] = 1;   // benign same-value race
        }
    }
    __syncthreads();

    // fused gather + straight-through write + f64 loss partial
    double local = 0.0;
    {
        const int cl8 = t >> 3;          // 0..31 (c row base)
        const int p4  = (t & 7) * 4;     // 0..28
        const int i0 = sbi[p4], i1 = sbi[p4 + 1], i2 = sbi[p4 + 2], i3 = sbi[p4 + 3];
#pragma unroll
        for (int it = 0; it < 4; ++it) {
            const int c = it * 32 + cl8;
            float4 xv = *reinterpret_cast<const float4*>(xb + (size_t)c * 1024 + p4);
            float q0 = emb[(size_t)i0 * DCH + c];
            float q1 = emb[(size_t)i1 * DCH + c];
            float q2 = emb[(size_t)i2 * DCH + c];
            float q3 = emb[(size_t)i3 * DCH + c];
            float d0 = q0 - xv.x, d1 = q1 - xv.y, d2 = q2 - xv.z, d3 = q3 - xv.w;
            float4 o = {xv.x + d0, xv.y + d1, xv.z + d2, xv.w + d3};
            *reinterpret_cast<float4*>(
                out0 + (size_t)(b * DCH + c) * 1024 + hw0 + p4) = o;
            local += (double)(d0 * d0);
            local += (double)(d1 * d1);
            local += (double)(d2 * d2);
            local += (double)(d3 * d3);
        }
    }
    // block f64 reduce (reuse et)
    double* sd = reinterpret_cast<double*>(&et[0][0]);
    sd[t] = local;
    __syncthreads();
    for (int s = 128; s > 0; s >>= 1) {
        if (t < s) sd[t] += sd[t + s];
        __syncthreads();
    }
    if (t == 0) partials[blockIdx.x] = sd[0];
}

// ---------------- finalize: loss + usage ----------------
__global__ __launch_bounds__(512) void vq_final(const double* __restrict__ partials,
                                                const int* __restrict__ flags,
                                                float* __restrict__ out_loss,
                                                float* __restrict__ out_usage) {
    __shared__ double sd[512];
    __shared__ int    si[512];
    const int t = threadIdx.x;
    double s = partials[t] + partials[t + 512];
    sd[t] = s;
    si[t] = flags[t];
    __syncthreads();
    for (int k = 256; k > 0; k >>= 1) {
        if (t < k) { sd[t] += sd[t + k]; si[t] += si[t + k]; }
        __syncthreads();
    }
    if (t == 0) {
        float m = (float)(sd[0] / (double)NELEM);
        *out_loss  = m + 0.25f * m;
        *out_usage = (float)si[0] / (float)KCODES;
    }
}

extern "C" void kernel_launch(void* const* d_in, const int* in_sizes, int n_in,
                              void* d_out, int out_size, void* d_ws, size_t ws_size,
                              hipStream_t stream) {
    const float* x   = (const float*)d_in[0];
    const float* emb = (const float*)d_in[1];
    float* out = (float*)d_out;

    float* out0      = out;
    float* out_loss  = out + OFF_LOSS;
    float* out_idx   = out + OFF_IDX;
    float* out_usage = out + OFF_USAGE;

    char* ws = (char*)d_ws;
    int*    ws_flags = (int*)ws;
    float*  ws_esq   = (float*)(ws + 2048);
    double* ws_part  = (double*)(ws + 4096);

    vq_prep <<<1,    512, 0, stream>>>(emb, ws_esq, ws_flags);
    vq_main <<<NBLK, NTHR, 0, stream>>>(x, emb, ws_esq, ws_flags, out0, out_idx, ws_part);
    vq_final<<<1,    512, 0, stream>>>(ws_part, ws_flags, out_loss, out_usage);
}

// Round 12
// 111.476 us; speedup vs baseline: 1.3659x; 1.2019x over previous
//
#include <hip/hip_runtime.h>
#include <hip/hip_bf16.h>

// x: [32,128,32,32] f32 -> N=32768 positions, D=128; emb: [512,128] f32.
// d_out: out0 quantized_st (4194304) | loss (1) | indices (32768) | usage (1)
//
// NUMERICS ARE CORRECTNESS-CRITICAL (verified passing rounds 2/4/5/6/..):
//  - esq/fsq: numpy pairwise 8-accumulator pattern, squares rounded pre-sum
//  - dot: single sequential FMA chain over c = 0..127 ascending
//  - dist: s = fl( fl(fsq + esq) - 2*dot ), tie -> lowest index
//  - loss: dq f32; square f32; accumulate f64
// Do not change per-element accumulation order.
//
// R12 change (perf only): R2-R11 analysis -> ~86us = ~39us VALU issue +
// ~50% stall; LDS/L2/HBM pipes all < limit. Stall = dependency latency at
// ~2 waves/SIMD. Fix: halve per-chunk LDS (et[8][512]=16KB, 16 chunks,
// block ~19.5KB vs 35.3KB) so more blocks (independent barrier groups)
// fit per CU. acc[8][8] + all arithmetic identical to R6 -> bit-identical
// outputs. R11's uniform-global-x experiment reverted (regressed +30us).

#define DCH    128
#define KCODES 512
#define NELEM  4194304
#define POSB   32          // positions per block
#define NBLK   1024        // 32768/32
#define NTHR   256
#define CCH    8           // c-rows per chunk
#define NCH    16          // chunks (128/8)

#define OFF_LOSS  4194304
#define OFF_IDX   4194305
#define OFF_USAGE 4227073

// ws layout: flags 512*4 @0 | esq 512*4 @2048 | partials 1024*8 @4096

__device__ __forceinline__ float round_barrier(float v) {
    asm volatile("" : "+v"(v));
    return v;
}

// ---------------- prep: ||e_k||^2 (numpy order) + zero flags ----------------
__global__ __launch_bounds__(512) void vq_prep(const float* __restrict__ emb,
                                               float* __restrict__ esq,
                                               int* __restrict__ flags) {
    int k = threadIdx.x;
    const float* row = emb + (size_t)k * DCH;
    float r[8];
#pragma unroll
    for (int j = 0; j < 8; ++j) { float v = row[j]; r[j] = round_barrier(v * v); }
#pragma unroll
    for (int i = 8; i < DCH; i += 8) {
#pragma unroll
        for (int j = 0; j < 8; ++j) {
            float v = row[i + j];
            float sq = round_barrier(v * v);
            r[j] += sq;
        }
    }
    esq[k] = ((r[0] + r[1]) + (r[2] + r[3])) + ((r[4] + r[5]) + (r[6] + r[7]));
    flags[k] = 0;
}

// ---------------- main: distances + argmin + gather/STE + loss partials ----
// 1024 blocks x 256 threads. Block: 32 positions vs all 512 codes.
// ty = wave (4 pos groups of 8), tx = lane. Lane owns codes {4tx..4tx+3} and
// {256+4tx..256+4tx+3}. acc[8][8]: i = position, j = code slot.
__global__ __launch_bounds__(256, 2) void vq_main(const float* __restrict__ x,
                                                  const float* __restrict__ emb,
                                                  const float* __restrict__ esq,
                                                  int* __restrict__ flags,
                                                  float* __restrict__ out0,
                                                  float* __restrict__ out_idx,
                                                  double* __restrict__ partials) {
    __shared__ __align__(16) float xt[CCH][32];     // 1 KB  (c-chunk x tile)
    __shared__ __align__(16) float et[CCH][512];    // 16 KB (c-chunk emb^T, swizzled)
    __shared__ float esq_s[KCODES];                 // 2 KB
    __shared__ float sfsq[POSB];
    __shared__ int   sbi[POSB];

    const int t   = threadIdx.x;
    const int n0  = blockIdx.x * POSB;
    const int b   = n0 >> 10;
    const int hw0 = n0 & 1023;
    const float* xb = x + (size_t)b * DCH * 1024 + hw0;

    // stage esq table
    esq_s[t]       = esq[t];
    esq_s[t + 256] = esq[t + 256];

    // fsq, numpy 8-accumulator: thread (p = t>>3, j = t&7) does r_j for pos p.
    // Partials in et scratch; consumed before chunk-0 staging (barrier).
    {
        const int p = t >> 3, j = t & 7;
        float r;
        {
            float v = xb[(size_t)j * 1024 + p];
            r = round_barrier(v * v);
        }
#pragma unroll
        for (int i = 1; i < 16; ++i) {
            float v = xb[(size_t)(8 * i + j) * 1024 + p];
            float sq = round_barrier(v * v);
            r += sq;
        }
        float (*sr)[POSB] = (float (*)[POSB]) & et[0][0];
        sr[j][p] = r;
    }
    __syncthreads();
    if (t < POSB) {
        float (*sr)[POSB] = (float (*)[POSB]) & et[0][0];
        sfsq[t] = ((sr[0][t] + sr[1][t]) + (sr[2][t] + sr[3][t]))
                + ((sr[4][t] + sr[5][t]) + (sr[6][t] + sr[7][t]));
    }

    const int ty = t >> 6;    // wave id = pos group
    const int tx = t & 63;    // lane

    float acc[8][8];
#pragma unroll
    for (int i = 0; i < 8; ++i)
#pragma unroll
        for (int j = 0; j < 8; ++j) acc[i][j] = 0.f;

    const int kst = t >> 1;   // staging: k lane base (0..127, +128r)
    const int jst = t & 1;    // float4 slot within 8-c chunk

    for (int cc = 0; cc < NCH; ++cc) {
        __syncthreads();  // prev compute done (and sr consumed at cc=0)

        // stage x chunk: xt[cl][p], cl = t>>5, p = t&31
        {
            const int cl = t >> 5;
            const int p  = t & 31;
            xt[cl][p] = xb[(size_t)(cc * CCH + cl) * 1024 + p];
        }
        // stage emb chunk transposed + XOR col swizzle: et[cl][k ^ (cl<<2)]
#pragma unroll
        for (int r = 0; r < 4; ++r) {
            const int k = kst + 128 * r;
            float4 v = *reinterpret_cast<const float4*>(
                emb + (size_t)k * DCH + cc * CCH + jst * 4);
            float va[4] = {v.x, v.y, v.z, v.w};
#pragma unroll
            for (int w = 0; w < 4; ++w) {
                const int cl = jst * 4 + w;
                et[cl][k ^ (cl << 2)] = va[w];
            }
        }
        __syncthreads();

        // 8x8 register tile; xt reads wave-uniform broadcasts; et reads
        // conflict-free b128 (granule = lane ^ uniform).
#pragma unroll
        for (int cl = 0; cl < CCH; ++cl) {
            const int s = cl << 2;   // compile-time per unrolled iter
            float4 xv0 = *reinterpret_cast<const float4*>(&xt[cl][ty * 8]);
            float4 xv1 = *reinterpret_cast<const float4*>(&xt[cl][ty * 8 + 4]);
            float4 ev0 = *reinterpret_cast<const float4*>(&et[cl][(tx * 4) ^ s]);
            float4 ev1 = *reinterpret_cast<const float4*>(&et[cl][256 + ((tx * 4) ^ s)]);
            float xa[8] = {xv0.x, xv0.y, xv0.z, xv0.w, xv1.x, xv1.y, xv1.z, xv1.w};
            float ea[8] = {ev0.x, ev0.y, ev0.z, ev0.w, ev1.x, ev1.y, ev1.z, ev1.w};
#pragma unroll
            for (int i = 0; i < 8; ++i)
#pragma unroll
                for (int j = 0; j < 8; ++j)
                    acc[i][j] = __builtin_fmaf(xa[i], ea[j], acc[i][j]);
        }
    }

    // fold distances + per-thread argmin (ascending global k within thread)
    float bd[8];
    int   bi[8];
#pragma unroll
    for (int i = 0; i < 8; ++i) { bd[i] = 3.4e38f; bi[i] = 0; }
#pragma unroll
    for (int j = 0; j < 8; ++j) {
        const int kg = (j < 4) ? (tx * 4 + j) : (256 + tx * 4 + (j - 4));
        const float eq = esq_s[kg];
#pragma unroll
        for (int i = 0; i < 8; ++i) {
            float A = sfsq[ty * 8 + i] + eq;   // rounds once (ulp ~1.5e-5)
            float s = A - 2.f * acc[i][j];     // 2*acc exact; rounds once
            if (s < bd[i]) { bd[i] = s; bi[i] = kg; }
        }
    }
    // 64-lane butterfly reduce, lexicographic (d, idx)
#pragma unroll
    for (int m = 1; m < 64; m <<= 1) {
#pragma unroll
        for (int i = 0; i < 8; ++i) {
            float d2 = __shfl_xor(bd[i], m, 64);
            int   i2 = __shfl_xor(bi[i], m, 64);
            if (d2 < bd[i] || (d2 == bd[i] && i2 < bi[i])) { bd[i] = d2; bi[i] = i2; }
        }
    }
    if (tx == 0) {
#pragma unroll
        for (int i = 0; i < 8; ++i) {
            const int p = ty * 8 + i;
            out_idx[n0 + p] = (float)bi[i];
            sbi[p] = bi[i];
            flags[bi[i]] = 1;   // benign same-value race
        }
    }
    __syncthreads();

    // fused gather + straight-through write + f64 loss partial
    double local = 0.0;
    {
        const int cl8 = t >> 3;          // 0..31 (c row base)
        const int p4  = (t & 7) * 4;     // 0..28
        const int i0 = sbi[p4], i1 = sbi[p4 + 1], i2 = sbi[p4 + 2], i3 = sbi[p4 + 3];
#pragma unroll
        for (int it = 0; it < 4; ++it) {
            const int c = it * 32 + cl8;
            float4 xv = *reinterpret_cast<const float4*>(xb + (size_t)c * 1024 + p4);
            float q0 = emb[(size_t)i0 * DCH + c];
            float q1 = emb[(size_t)i1 * DCH + c];
            float q2 = emb[(size_t)i2 * DCH + c];
            float q3 = emb[(size_t)i3 * DCH + c];
            float d0 = q0 - xv.x, d1 = q1 - xv.y, d2 = q2 - xv.z, d3 = q3 - xv.w;
            float4 o = {xv.x + d0, xv.y + d1, xv.z + d2, xv.w + d3};
            *reinterpret_cast<float4*>(
                out0 + (size_t)(b * DCH + c) * 1024 + hw0 + p4) = o;
            local += (double)(d0 * d0);
            local += (double)(d1 * d1);
            local += (double)(d2 * d2);
            local += (double)(d3 * d3);
        }
    }
    // block f64 reduce (reuse et; last reads were before the post-fold barrier)
    double* sd = reinterpret_cast<double*>(&et[0][0]);
    sd[t] = local;
    __syncthreads();
    for (int s = 128; s > 0; s >>= 1) {
        if (t < s) sd[t] += sd[t + s];
        __syncthreads();
    }
    if (t == 0) partials[blockIdx.x] = sd[0];
}

// ---------------- finalize: loss + usage ----------------
__global__ __launch_bounds__(512) void vq_final(const double* __restrict__ partials,
                                                const int* __restrict__ flags,
                                                float* __restrict__ out_loss,
                                                float* __restrict__ out_usage) {
    __shared__ double sd[512];
    __shared__ int    si[512];
    const int t = threadIdx.x;
    double s = partials[t] + partials[t + 512];
    sd[t] = s;
    si[t] = flags[t];
    __syncthreads();
    for (int k = 256; k > 0; k >>= 1) {
        if (t < k) { sd[t] += sd[t + k]; si[t] += si[t + k]; }
        __syncthreads();
    }
    if (t == 0) {
        float m = (float)(sd[0] / (double)NELEM);
        *out_loss  = m + 0.25f * m;
        *out_usage = (float)si[0] / (float)KCODES;
    }
}

extern "C" void kernel_launch(void* const* d_in, const int* in_sizes, int n_in,
                              void* d_out, int out_size, void* d_ws, size_t ws_size,
                              hipStream_t stream) {
    const float* x   = (const float*)d_in[0];
    const float* emb = (const float*)d_in[1];
    float* out = (float*)d_out;

    float* out0      = out;
    float* out_loss  = out + OFF_LOSS;
    float* out_idx   = out + OFF_IDX;
    float* out_usage = out + OFF_USAGE;

    char* ws = (char*)d_ws;
    int*    ws_flags = (int*)ws;
    float*  ws_esq   = (float*)(ws + 2048);
    double* ws_part  = (double*)(ws + 4096);

    vq_prep <<<1,    512, 0, stream>>>(emb, ws_esq, ws_flags);
    vq_main <<<NBLK, NTHR, 0, stream>>>(x, emb, ws_esq, ws_flags, out0, out_idx, ws_part);
    vq_final<<<1,    512, 0, stream>>>(ws_part, ws_flags, out_loss, out_usage);
}